// Round 1
// baseline (537.070 us; speedup 1.0000x reference)
//
#include <hip/hip_runtime.h>

// Problem constants (from reference): N=4194304 rows, C=16 classes, EPS=1.0
// Segments: 4 signal (rows >= signal_start), 8 background (rows < signal_start).
// Workspace layout: [0,8) double loss_sum; [8,8+24*4) uint counters:
//   ctr[0..3]  = fn (signal mismatch count per sig segment)
//   ctr[4..7]  = cnt (signal rows per sig segment)
//   ctr[8..15] = fns (background hit count per bg segment)
//   ctr[16..23]= cnt_b (background rows per bg segment)

__global__ void init_ws(double* loss_sum, unsigned int* ctr) {
    if (threadIdx.x == 0) *loss_sum = 0.0;
    if (threadIdx.x < 24) ctr[threadIdx.x] = 0u;
}

__global__ __launch_bounds__(256) void zscore_main(
    const float4* __restrict__ pred,   // N rows x 4 float4 (16 classes)
    const float4* __restrict__ truth,
    const int*    __restrict__ sig_ids,
    const int*    __restrict__ bg_ids,
    int N, int signal_start,
    double* __restrict__ loss_sum,
    unsigned int* __restrict__ ctr)
{
    // s_flag/s_cnt indexed by p: p in [0,4) = signal seg, p in [4,12) = 4+bg seg
    __shared__ unsigned int s_flag[12];
    __shared__ unsigned int s_cnt[12];
    __shared__ float s_wave_loss[4];

    const int tid = threadIdx.x;
    if (tid < 12) { s_flag[tid] = 0u; s_cnt[tid] = 0u; }
    __syncthreads();

    const int T = gridDim.x * blockDim.x;
    float local_loss = 0.0f;

    // NOTE: N % 64 == 0 (4194304) and T % 64 == 0, so every wave is either
    // fully in-range or fully out -> wave intrinsics below see full waves.
    for (int row = blockIdx.x * blockDim.x + tid; row < N; row += T) {
        const float4* pr = pred  + (size_t)row * 4;
        const float4* tr = truth + (size_t)row * 4;
        float4 p0 = pr[0], p1 = pr[1], p2 = pr[2], p3 = pr[3];
        float4 t0 = tr[0], t1 = tr[1], t2 = tr[2], t3 = tr[3];

        float v[16] = {p0.x,p0.y,p0.z,p0.w, p1.x,p1.y,p1.z,p1.w,
                       p2.x,p2.y,p2.z,p2.w, p3.x,p3.y,p3.z,p3.w};
        float t[16] = {t0.x,t0.y,t0.z,t0.w, t1.x,t1.y,t1.z,t1.w,
                       t2.x,t2.y,t2.z,t2.w, t3.x,t3.y,t3.z,t3.w};

        // pred argmax (first max wins, matching jnp.argmax) + max for logsumexp
        float pm = v[0]; int am = 0;
        #pragma unroll
        for (int i = 1; i < 16; ++i) { if (v[i] > pm) { pm = v[i]; am = i; } }

        // truth argmax (one-hot -> index of the 1)
        float tmx = t[0]; int tm = 0;
        #pragma unroll
        for (int i = 1; i < 16; ++i) { if (t[i] > tmx) { tmx = t[i]; tm = i; } }

        // logsumexp
        float s = 0.0f;
        #pragma unroll
        for (int i = 0; i < 16; ++i) s += __expf(v[i] - pm);
        float lse = pm + __logf(s);

        // pred[tm] via cndmask chain (avoid dynamic indexing -> no scratch)
        float pv = v[0];
        #pragma unroll
        for (int i = 1; i < 16; ++i) pv = (i == tm) ? v[i] : pv;

        local_loss += lse - pv;  // -(log_softmax[tm])

        // segment statistics
        bool isSig = row >= signal_start;
        int p; bool flag;
        if (isSig) { p = sig_ids[row - signal_start]; flag = (am != tm); }
        else       { p = 4 + bg_ids[row];             flag = (am == 0);  }

        int p0l = __builtin_amdgcn_readfirstlane(p);
        bool uni = __all(p == p0l);
        if (uni) {
            unsigned long long fb = __ballot(flag);
            unsigned long long ab = __ballot(true);
            if ((tid & 63) == 0) {
                atomicAdd(&s_cnt[p0l],  (unsigned int)__popcll(ab));
                atomicAdd(&s_flag[p0l], (unsigned int)__popcll(fb));
            }
        } else {
            atomicAdd(&s_cnt[p], 1u);
            if (flag) atomicAdd(&s_flag[p], 1u);
        }
    }

    // reduce local_loss: wave shuffle -> LDS -> block -> global double atomic
    #pragma unroll
    for (int off = 32; off > 0; off >>= 1)
        local_loss += __shfl_down(local_loss, off);
    if ((tid & 63) == 0) s_wave_loss[tid >> 6] = local_loss;
    __syncthreads();

    if (tid == 0) {
        float bl = s_wave_loss[0] + s_wave_loss[1] + s_wave_loss[2] + s_wave_loss[3];
        atomicAdd(loss_sum, (double)bl);
    }
    if (tid < 12) {
        int fIdx = (tid < 4) ? tid       : 8  + (tid - 4);
        int cIdx = (tid < 4) ? 4 + tid   : 16 + (tid - 4);
        if (s_flag[tid]) atomicAdd(&ctr[fIdx], s_flag[tid]);
        if (s_cnt[tid])  atomicAdd(&ctr[cIdx], s_cnt[tid]);
    }
}

__global__ void finalize(const float* __restrict__ w_sig,
                         const float* __restrict__ w_bg,
                         const double* __restrict__ loss_sum,
                         const unsigned int* __restrict__ ctr,
                         float* __restrict__ out, int N)
{
    if (threadIdx.x != 0 || blockIdx.x != 0) return;
    double sig = 0.0, wsum = 0.0;
    for (int s = 0; s < 4; ++s) {
        double cnt = (double)ctr[4 + s];
        double fn  = (double)ctr[s];
        sig  += (cnt - fn) / cnt * (double)w_sig[s];
        wsum += (double)w_sig[s];
    }
    double bg = 0.0;
    for (int s = 0; s < 8; ++s) {
        double fns = (double)ctr[8 + s];
        double cb  = (double)ctr[16 + s];
        bg += sqrt(fns / cb * (double)w_bg[s] + 1.0);  // EPS = 1.0
    }
    double coeff = (wsum - sig) / bg;   // max_score = wsum / sqrt(1.0)
    double loss  = (*loss_sum) / (double)N;
    out[0] = (float)(loss * coeff);
}

extern "C" void kernel_launch(void* const* d_in, const int* in_sizes, int n_in,
                              void* d_out, int out_size, void* d_ws, size_t ws_size,
                              hipStream_t stream) {
    const float* pred   = (const float*)d_in[0];
    const float* truth  = (const float*)d_in[1];
    const float* w_sig  = (const float*)d_in[2];
    const float* w_bg   = (const float*)d_in[3];
    const int*   sigid  = (const int*)d_in[4];
    const int*   bgid   = (const int*)d_in[5];

    const int N = in_sizes[0] / 16;          // rows
    const int signal_start = in_sizes[5];    // == len(background_seg_ids) == B_BG

    double*       loss_sum = (double*)d_ws;
    unsigned int* ctr      = (unsigned int*)((char*)d_ws + 8);

    init_ws<<<1, 64, 0, stream>>>(loss_sum, ctr);

    const int blocks = 1024;                 // 4 blocks/CU, 16 waves/CU
    zscore_main<<<blocks, 256, 0, stream>>>(
        (const float4*)pred, (const float4*)truth, sigid, bgid,
        N, signal_start, loss_sum, ctr);

    finalize<<<1, 64, 0, stream>>>(w_sig, w_bg, loss_sum, ctr, (float*)d_out, N);
}